// Round 10
// baseline (152.802 us; speedup 1.0000x reference)
//
#include <hip/hip_runtime.h>
#include <hip/hip_bf16.h>
#include <stdint.h>

#define SDEP 128
#define NRES 256
#define CZQ 128

typedef __bf16 v8bf __attribute__((ext_vector_type(8)));
typedef __bf16 v4bf __attribute__((ext_vector_type(4)));
typedef float v16f __attribute__((ext_vector_type(16)));

// full-wave sum via DPP (VALU pipe, no LDS). Result valid in lane 63.
__device__ __forceinline__ float dpp_wave_sum(float x) {
  float t;
#define STEP(ctrl)                                                         \
  t = __builtin_bit_cast(float, __builtin_amdgcn_update_dpp(               \
          0, __builtin_bit_cast(int, x), ctrl, 0xF, 0xF, true));           \
  x += t;
  STEP(0x111)
  STEP(0x112)
  STEP(0x114)
  STEP(0x118)
  STEP(0x142)
  STEP(0x143)
#undef STEP
  return x;
}
__device__ __forceinline__ float lane63(float x) {
  return __builtin_bit_cast(float,
      __builtin_amdgcn_readlane(__builtin_bit_cast(int, x), 63));
}

#define MFMA32(a, b, c) __builtin_amdgcn_mfma_f32_32x32x16_bf16(a, b, c, 0, 0, 0)

// ---------------- Kernel A: fused prep + LN + projections ------------
// R16 = R14 (proven, fusedA ~13.7us) + LN load-hoist: all 8 row-loads
// issued into xv[8] BEFORE the DPP chains -> one HBM-latency exposure
// per wave instead of eight. Tails identical to R14.
__global__ __launch_bounds__(256, 4) void fusedA_kernel(
    const float* __restrict__ msa, const float* __restrict__ lnw,
    const float* __restrict__ lnb, const float* __restrict__ wl,
    const float* __restrict__ wr, const float* __restrict__ mask,
    const float* __restrict__ wo, const float* __restrict__ bl,
    const float* __restrict__ br,
    __bf16* __restrict__ At2, __bf16* __restrict__ Bt2,
    float* __restrict__ rnorm, __bf16* __restrict__ wot4)
{
  __shared__ __bf16 xs[32 * 258];       // 16512 B  LN rows (local s-block)
  __shared__ float  LsF[2 * 1024];      //  8192 B  kh=1 GEMM partials
  __shared__ __bf16 LsT[2 * 32 * 36];   //  4608 B  transpose staging

  const int bi = blockIdx.x;            // 0..1023
  const int i = bi >> 2;                // res column 0..255
  const int sb = bi & 3;                // s-block 0..3 (32 rows each)
  const int t = threadIdx.x;
  const int w = t >> 6, lane = t & 63;
  const int half = lane >> 5, l31 = lane & 31;
  const int nh = w & 1;                 // 0 = A (wl), 1 = B (wr)
  const int kh = w >> 1;                // K-half of GEMM

  // ---- LN: 8 rows per wave; loads hoisted (8 in flight) ----
  const float4 wv4 = ((const float4*)lnw)[lane];
  const float4 bv4 = ((const float4*)lnb)[lane];
  const int s0 = sb * 32 + w * 8;
  float4 xv[8];
  #pragma unroll
  for (int r = 0; r < 8; ++r)
    xv[r] = ((const float4*)(msa + ((size_t)(s0 + r) * 256 + i) * 256))[lane];
  #pragma unroll
  for (int r = 0; r < 8; ++r) {
    float4 x = xv[r];
    float s1 = dpp_wave_sum(x.x + x.y + x.z + x.w);
    float s2 = dpp_wave_sum(x.x * x.x + x.y * x.y + x.z * x.z + x.w * x.w);
    float mu = lane63(s1) * (1.f / 256.f);
    float var = lane63(s2) * (1.f / 256.f) - mu * mu;
    float rs = rsqrtf(var + 1e-5f);
    v4bf o;
    o[0] = (__bf16)((x.x - mu) * rs * wv4.x + bv4.x);
    o[1] = (__bf16)((x.y - mu) * rs * wv4.y + bv4.y);
    o[2] = (__bf16)((x.z - mu) * rs * wv4.z + bv4.z);
    o[3] = (__bf16)((x.w - mu) * rs * wv4.w + bv4.w);
    *(v4bf*)(xs + (w * 8 + r) * 258 + lane * 4) = o;
  }

  // ---- weight fragments (direct global, L2-hot; overlaps LN drain) ----
  const float* wsrc = nh ? wr : wl;
  v8bf bfr[8];
  #pragma unroll
  for (int ks = 0; ks < 8; ++ks) {
    const int ksg = kh * 8 + ks;
    float tmp[8];
    #pragma unroll
    for (int e = 0; e < 8; ++e)
      tmp[e] = wsrc[(ksg * 16 + half * 8 + e) * 32 + l31];
    v8bf bb;
    #pragma unroll
    for (int e = 0; e < 8; ++e) bb[e] = (__bf16)tmp[e];
    bfr[ks] = bb;
  }

  __syncthreads();  // xs ready

  // ---- GEMM: 8 MFMA per wave (K-half kh) ----
  v16f acc;
  #pragma unroll
  for (int r = 0; r < 16; ++r) acc[r] = 0.f;
  const __bf16* xrow = xs + l31 * 258 + half * 8;
  #pragma unroll
  for (int ks = 0; ks < 8; ++ks) {
    v8bf a = *(const v8bf*)(xrow + (kh * 8 + ks) * 16);
    acc = MFMA32(a, bfr[ks], acc);
  }

  if (kh == 1) {
    #pragma unroll
    for (int r = 0; r < 16; ++r) {
      int cc = (r & 3) + 8 * (r >> 2) + 4 * half;
      LsF[nh * 1024 + cc * 32 + l31] = acc[r];
    }
  }
  __syncthreads();  // partials ready

  if (kh == 0) {
    const float bias = (nh ? br : bl)[l31];
    __bf16* Lw = LsT + nh * (32 * 36);
    #pragma unroll
    for (int r = 0; r < 16; ++r) {
      int sl = (r & 3) + 8 * (r >> 2) + 4 * half;
      float mv = mask[(sb * 32 + sl) * NRES + i];
      float v = acc[r] + LsF[nh * 1024 + sl * 32 + l31] + bias;
      Lw[l31 * 36 + sl] = (__bf16)(v * mv);
    }
    __bf16* dst = nh ? Bt2 : At2;
    const int c = lane >> 1, jq = (lane & 1) * 4;
    #pragma unroll
    for (int o = 0; o < 4; ++o) {
      v4bf v = *(const v4bf*)(Lw + c * 36 + o * 8 + jq);
      *(v4bf*)(dst + ((size_t)i * 16 + sb * 4 + o) * 256 + lane * 4) = v;
    }
  }

  // ---- distributed tail (R14 form, proven) ----
  if (w == 3) {
    // rnorm: row i, cols sb*64 .. +64 (64 lanes, one 128-dot each)
    const int col = sb * 64 + lane;
    float a0 = 0.f;
    #pragma unroll 8
    for (int s = 0; s < SDEP; ++s)
      a0 += mask[s * NRES + i] * mask[s * NRES + col];
    rnorm[i * NRES + col] = 1.f / fmaxf(a0, 1.f);
  } else if (w == 1 || w == 2) {
    // wot4: 128 elements per block
    const int idx = bi * 128 + (t - 64);
    int j = idx & 7, lc = (idx >> 3) & 63, kk = (idx >> 9) & 63, zg = idx >> 15;
    int k = kk * 16 + (lc >> 5) * 8 + j;
    int z = zg * 32 + (lc & 31);
    wot4[idx] = (__bf16)wo[k * CZQ + z];
  }
}

// ---------------- Kernel B: dual-tile outer-product-mean + out proj ---
// R16 = R8 body (proven 52.4-52.7 us x3, natural block order) with ONE
// change: G2 wot ring depth 8 -> 16.
//  - 16 elems prefetched BEFORE the Ps LDS-write block (loads drain
//    under ~128 LDS writes + barrier instead of stalling G2).
//  - in-loop distance 16 kk-steps (~500 cyc) >> L2 latency: slot algebra
//    kk in [16,32) reads wb[kk&15] written at kk-16 (read-then-write).
__global__ __launch_bounds__(512, 2) void outer_kernel(
    const __bf16* __restrict__ At2, const __bf16* __restrict__ Bt2,
    const float* __restrict__ rnorm, const __bf16* __restrict__ wot4,
    const float* __restrict__ bo, float* __restrict__ out)
{
  __shared__ __bf16 Ps[2][32 * 1032];   // 132096 B  [tile][p][c*32+d]
  __shared__ __bf16 redb[2][4 * 1024];  // 16384 B   [tile][zg][cc*32+l31]

  const int tid = threadIdx.x;
  const int w = tid >> 6, lane = tid & 63;
  const int half = lane >> 5, l31 = lane & 31;
  const int bxp = blockIdx.x;           // 0..15 -> j units bxp*16 .. +15
  const int by = blockIdx.y;            // 0..63 -> i units by*4 .. +3
  const int mh = w >> 2;                // i-pair (0..1)     [GEMM1 role]
  const int nq = w & 3;                 // j-pair (0..3)
  const int zg = w & 3;                 // z-quarter (0..3)  [GEMM2 role]
  const int kh = w >> 2;                // K-half (0..1)

  // ---- GEMM1 dual: 64x64 quadrant per wave, two B panels, shared A ----
  const __bf16* Ap  = At2 + ((size_t)(by * 4 + mh * 2)) * 4096 + l31 * 8;
  const __bf16* Bpa = Bt2 + ((size_t)(bxp * 16 + nq * 2)) * 4096 + l31 * 8;
  const __bf16* Bpb = Bpa + 8 * 4096;

  v16f aca[2][2], acb[2][2];
  #pragma unroll
  for (int a = 0; a < 2; ++a)
    #pragma unroll
    for (int b = 0; b < 2; ++b)
      #pragma unroll
      for (int r = 0; r < 16; ++r) { aca[a][b][r] = 0.f; acb[a][b][r] = 0.f; }

  #pragma unroll
  for (int ks = 0; ks < 8; ++ks) {
    const int off = (ks * 2 + half) * 256;
    v8bf a0  = *(const v8bf*)(Ap + off);
    v8bf a1  = *(const v8bf*)(Ap + 4096 + off);
    v8bf b0a = *(const v8bf*)(Bpa + off);
    v8bf b1a = *(const v8bf*)(Bpa + 4096 + off);
    v8bf b0b = *(const v8bf*)(Bpb + off);
    v8bf b1b = *(const v8bf*)(Bpb + 4096 + off);
    aca[0][0] = MFMA32(a0, b0a, aca[0][0]);
    aca[0][1] = MFMA32(a0, b1a, aca[0][1]);
    aca[1][0] = MFMA32(a1, b0a, aca[1][0]);
    aca[1][1] = MFMA32(a1, b1a, aca[1][1]);
    acb[0][0] = MFMA32(a0, b0b, acb[0][0]);
    acb[0][1] = MFMA32(a0, b1b, acb[0][1]);
    acb[1][0] = MFMA32(a1, b0b, acb[1][0]);
    acb[1][1] = MFMA32(a1, b1b, acb[1][1]);
  }

  // ---- GEMM2 wot prefetch (16 deep): issue BEFORE the Ps writes ----
  const __bf16* wp =
      wot4 + ((size_t)((zg * 64 + kh * 32) * 64) + half * 32 + l31) * 8;
  v8bf wb[16];
  #pragma unroll
  for (int u = 0; u < 16; ++u)
    wb[u] = *(const v8bf*)(wp + u * 512);
  const float bz = bo[zg * 32 + l31];

  // ---- P writes for both tiles: P[p][c*32+d] = outer * rnorm ----
  #pragma unroll
  for (int ti = 0; ti < 2; ++ti) {
    #pragma unroll
    for (int tj = 0; tj < 2; ++tj) {
      const int it = mh * 2 + ti, jt = nq * 2 + tj;
      const int p = it * 8 + jt;
      const float rna = rnorm[(by * 4 + it) * NRES + bxp * 16 + jt];
      const float rnb = rnorm[(by * 4 + it) * NRES + bxp * 16 + 8 + jt];
      #pragma unroll
      for (int r = 0; r < 16; ++r) {
        int cc = (r & 3) + 8 * (r >> 2) + 4 * half;
        Ps[0][p * 1032 + cc * 32 + l31] = (__bf16)(aca[ti][tj][r] * rna);
        Ps[1][p * 1032 + cc * 32 + l31] = (__bf16)(acb[ti][tj][r] * rnb);
      }
    }
  }

  __syncthreads();

  // ---- GEMM2 dual: one wot stream feeds both tiles (K-split kh) ----
  const __bf16* ppa = &Ps[0][l31 * 1032 + kh * 512 + half * 8];
  const __bf16* ppb = &Ps[1][l31 * 1032 + kh * 512 + half * 8];

  v16f c2a, c2b;
  #pragma unroll
  for (int r = 0; r < 16; ++r) { c2a[r] = 0.f; c2b[r] = 0.f; }

  #pragma unroll
  for (int g = 0; g < 4; ++g) {
    #pragma unroll
    for (int u = 0; u < 8; ++u) {
      const int kk = g * 8 + u;
      v8bf bb = wb[kk & 15];
      if (g < 2) wb[kk & 15] = *(const v8bf*)(wp + (kk + 16) * 512);
      v8bf aaa = *(const v8bf*)(ppa + kk * 16);
      v8bf aab = *(const v8bf*)(ppb + kk * 16);
      c2a = MFMA32(aaa, bb, c2a);
      c2b = MFMA32(aab, bb, c2b);
    }
  }

  // kh==1 partials -> bf16 region (no Ps aliasing, no extra barrier)
  if (kh == 1) {
    #pragma unroll
    for (int r = 0; r < 16; ++r) {
      int cc = (r & 3) + 8 * (r >> 2) + 4 * half;
      redb[0][zg * 1024 + cc * 32 + l31] = (__bf16)c2a[r];
      redb[1][zg * 1024 + cc * 32 + l31] = (__bf16)c2b[r];
    }
  }
  __syncthreads();

  if (kh == 0) {
    #pragma unroll
    for (int r = 0; r < 16; ++r) {
      int cc = (r & 3) + 8 * (r >> 2) + 4 * half;   // = p row
      int i = by * 4 + (cc >> 3);
      float va = c2a[r] + (float)redb[0][zg * 1024 + cc * 32 + l31] + bz;
      float vb = c2b[r] + (float)redb[1][zg * 1024 + cc * 32 + l31] + bz;
      out[((size_t)i * NRES + bxp * 16 + (cc & 7)) * CZQ + zg * 32 + l31] = va;
      out[((size_t)i * NRES + bxp * 16 + 8 + (cc & 7)) * CZQ + zg * 32 + l31] = vb;
    }
  }
}

extern "C" void kernel_launch(void* const* d_in, const int* in_sizes, int n_in,
                              void* d_out, int out_size, void* d_ws, size_t ws_size,
                              hipStream_t stream) {
  const float* msa  = (const float*)d_in[0];
  const float* mask = (const float*)d_in[1];
  const float* lnw  = (const float*)d_in[2];
  const float* lnb  = (const float*)d_in[3];
  const float* wl   = (const float*)d_in[4];
  const float* bl   = (const float*)d_in[5];
  const float* wr   = (const float*)d_in[6];
  const float* br   = (const float*)d_in[7];
  const float* wo   = (const float*)d_in[8];
  const float* bo   = (const float*)d_in[9];
  float* out = (float*)d_out;

  char* ws = (char*)d_ws;
  __bf16* At2   = (__bf16*)(ws);                    // 2 MB
  __bf16* Bt2   = (__bf16*)(ws + 2097152);          // 2 MB
  float*  rnorm = (float*)(ws + 4194304);           // 256 KB
  __bf16* wot4  = (__bf16*)(ws + 4456448);          // 256 KB

  fusedA_kernel<<<1024, 256, 0, stream>>>(msa, lnw, lnb, wl, wr, mask, wo,
                                          bl, br, At2, Bt2, rnorm, wot4);
  outer_kernel<<<dim3(16, 64), 512, 0, stream>>>(At2, Bt2, rnorm, wot4, bo, out);
}

// Round 11
// 148.112 us; speedup vs baseline: 1.0317x; 1.0317x over previous
//
#include <hip/hip_runtime.h>
#include <hip/hip_bf16.h>
#include <stdint.h>

#define SDEP 128
#define NRES 256
#define CZQ 128

typedef __bf16 v8bf __attribute__((ext_vector_type(8)));
typedef __bf16 v4bf __attribute__((ext_vector_type(4)));
typedef float v16f __attribute__((ext_vector_type(16)));

// full-wave sum via DPP (VALU pipe, no LDS). Result valid in lane 63.
__device__ __forceinline__ float dpp_wave_sum(float x) {
  float t;
#define STEP(ctrl)                                                         \
  t = __builtin_bit_cast(float, __builtin_amdgcn_update_dpp(               \
          0, __builtin_bit_cast(int, x), ctrl, 0xF, 0xF, true));           \
  x += t;
  STEP(0x111)
  STEP(0x112)
  STEP(0x114)
  STEP(0x118)
  STEP(0x142)
  STEP(0x143)
#undef STEP
  return x;
}
__device__ __forceinline__ float lane63(float x) {
  return __builtin_bit_cast(float,
      __builtin_amdgcn_readlane(__builtin_bit_cast(int, x), 63));
}

#define MFMA32(a, b, c) __builtin_amdgcn_mfma_f32_32x32x16_bf16(a, b, c, 0, 0, 0)

// ---------------- Kernel A: fused prep + LN + projections ------------
// R17 = exact R14 (best measured fusedA, ~13.7 us).
// 1024 blocks x 256 thr (4 waves), one block per (i, s-block of 32).
__global__ __launch_bounds__(256, 4) void fusedA_kernel(
    const float* __restrict__ msa, const float* __restrict__ lnw,
    const float* __restrict__ lnb, const float* __restrict__ wl,
    const float* __restrict__ wr, const float* __restrict__ mask,
    const float* __restrict__ wo, const float* __restrict__ bl,
    const float* __restrict__ br,
    __bf16* __restrict__ At2, __bf16* __restrict__ Bt2,
    float* __restrict__ rnorm, __bf16* __restrict__ wot4)
{
  __shared__ __bf16 xs[32 * 258];       // 16512 B  LN rows (local s-block)
  __shared__ float  LsF[2 * 1024];      //  8192 B  kh=1 GEMM partials
  __shared__ __bf16 LsT[2 * 32 * 36];   //  4608 B  transpose staging

  const int bi = blockIdx.x;            // 0..1023
  const int i = bi >> 2;                // res column 0..255
  const int sb = bi & 3;                // s-block 0..3 (32 rows each)
  const int t = threadIdx.x;
  const int w = t >> 6, lane = t & 63;
  const int half = lane >> 5, l31 = lane & 31;
  const int nh = w & 1;                 // 0 = A (wl), 1 = B (wr)
  const int kh = w >> 1;                // K-half of GEMM

  // ---- LN: 8 rows per wave ----
  const float4 wv4 = ((const float4*)lnw)[lane];
  const float4 bv4 = ((const float4*)lnb)[lane];
  const int s0 = sb * 32 + w * 8;
  #pragma unroll
  for (int r = 0; r < 8; ++r) {
    const int s = s0 + r;
    float4 x = ((const float4*)(msa + ((size_t)s * 256 + i) * 256))[lane];
    float s1 = dpp_wave_sum(x.x + x.y + x.z + x.w);
    float s2 = dpp_wave_sum(x.x * x.x + x.y * x.y + x.z * x.z + x.w * x.w);
    float mu = lane63(s1) * (1.f / 256.f);
    float var = lane63(s2) * (1.f / 256.f) - mu * mu;
    float rs = rsqrtf(var + 1e-5f);
    v4bf o;
    o[0] = (__bf16)((x.x - mu) * rs * wv4.x + bv4.x);
    o[1] = (__bf16)((x.y - mu) * rs * wv4.y + bv4.y);
    o[2] = (__bf16)((x.z - mu) * rs * wv4.z + bv4.z);
    o[3] = (__bf16)((x.w - mu) * rs * wv4.w + bv4.w);
    *(v4bf*)(xs + (w * 8 + r) * 258 + lane * 4) = o;
  }

  // ---- weight fragments (direct global, L2-hot; overlaps LN drain) ----
  const float* wsrc = nh ? wr : wl;
  v8bf bfr[8];
  #pragma unroll
  for (int ks = 0; ks < 8; ++ks) {
    const int ksg = kh * 8 + ks;
    float tmp[8];
    #pragma unroll
    for (int e = 0; e < 8; ++e)
      tmp[e] = wsrc[(ksg * 16 + half * 8 + e) * 32 + l31];
    v8bf bb;
    #pragma unroll
    for (int e = 0; e < 8; ++e) bb[e] = (__bf16)tmp[e];
    bfr[ks] = bb;
  }

  __syncthreads();  // xs ready

  // ---- GEMM: 8 MFMA per wave (K-half kh) ----
  v16f acc;
  #pragma unroll
  for (int r = 0; r < 16; ++r) acc[r] = 0.f;
  const __bf16* xrow = xs + l31 * 258 + half * 8;
  #pragma unroll
  for (int ks = 0; ks < 8; ++ks) {
    v8bf a = *(const v8bf*)(xrow + (kh * 8 + ks) * 16);
    acc = MFMA32(a, bfr[ks], acc);
  }

  if (kh == 1) {
    #pragma unroll
    for (int r = 0; r < 16; ++r) {
      int cc = (r & 3) + 8 * (r >> 2) + 4 * half;
      LsF[nh * 1024 + cc * 32 + l31] = acc[r];
    }
  }
  __syncthreads();  // partials ready

  if (kh == 0) {
    const float bias = (nh ? br : bl)[l31];
    __bf16* Lw = LsT + nh * (32 * 36);
    #pragma unroll
    for (int r = 0; r < 16; ++r) {
      int sl = (r & 3) + 8 * (r >> 2) + 4 * half;
      float mv = mask[(sb * 32 + sl) * NRES + i];
      float v = acc[r] + LsF[nh * 1024 + sl * 32 + l31] + bias;
      Lw[l31 * 36 + sl] = (__bf16)(v * mv);
    }
    __bf16* dst = nh ? Bt2 : At2;
    const int c = lane >> 1, jq = (lane & 1) * 4;
    #pragma unroll
    for (int o = 0; o < 4; ++o) {
      v4bf v = *(const v4bf*)(Lw + c * 36 + o * 8 + jq);
      *(v4bf*)(dst + ((size_t)i * 16 + sb * 4 + o) * 256 + lane * 4) = v;
    }
  }

  // ---- distributed tail (no barrier needed; independent outputs) ----
  if (w == 3) {
    // rnorm: row i, cols sb*64 .. +64 (64 lanes, one 128-dot each)
    const int col = sb * 64 + lane;
    float a0 = 0.f;
    #pragma unroll 8
    for (int s = 0; s < SDEP; ++s)
      a0 += mask[s * NRES + i] * mask[s * NRES + col];
    rnorm[i * NRES + col] = 1.f / fmaxf(a0, 1.f);
  } else if (w == 1 || w == 2) {
    // wot4: 128 elements per block
    const int idx = bi * 128 + (t - 64);
    int j = idx & 7, lc = (idx >> 3) & 63, kk = (idx >> 9) & 63, zg = idx >> 15;
    int k = kk * 16 + (lc >> 5) * 8 + j;
    int z = zg * 32 + (lc & 31);
    wot4[idx] = (__bf16)wo[k * CZQ + z];
  }
}

// ---------------- Kernel B: dual-tile outer-product-mean + out proj ---
// R17 = exact R8 body (proven 52.4-52.7 us x3).
//  each block covers 4i x 16j = TWO 4x8 tiles sharing ONE wot pass.
//  grid (16,64) = 1024 short-lived blocks, natural order.
__global__ __launch_bounds__(512, 2) void outer_kernel(
    const __bf16* __restrict__ At2, const __bf16* __restrict__ Bt2,
    const float* __restrict__ rnorm, const __bf16* __restrict__ wot4,
    const float* __restrict__ bo, float* __restrict__ out)
{
  __shared__ __bf16 Ps[2][32 * 1032];   // 132096 B  [tile][p][c*32+d]
  __shared__ __bf16 redb[2][4 * 1024];  // 16384 B   [tile][zg][cc*32+l31]

  const int tid = threadIdx.x;
  const int w = tid >> 6, lane = tid & 63;
  const int half = lane >> 5, l31 = lane & 31;
  const int bxp = blockIdx.x;           // 0..15 -> j units bxp*16 .. +15
  const int by = blockIdx.y;            // 0..63 -> i units by*4 .. +3
  const int mh = w >> 2;                // i-pair (0..1)     [GEMM1 role]
  const int nq = w & 3;                 // j-pair (0..3)
  const int zg = w & 3;                 // z-quarter (0..3)  [GEMM2 role]
  const int kh = w >> 2;                // K-half (0..1)

  // ---- GEMM1 dual: 64x64 quadrant per wave, two B panels, shared A ----
  const __bf16* Ap  = At2 + ((size_t)(by * 4 + mh * 2)) * 4096 + l31 * 8;
  const __bf16* Bpa = Bt2 + ((size_t)(bxp * 16 + nq * 2)) * 4096 + l31 * 8;
  const __bf16* Bpb = Bpa + 8 * 4096;

  v16f aca[2][2], acb[2][2];
  #pragma unroll
  for (int a = 0; a < 2; ++a)
    #pragma unroll
    for (int b = 0; b < 2; ++b)
      #pragma unroll
      for (int r = 0; r < 16; ++r) { aca[a][b][r] = 0.f; acb[a][b][r] = 0.f; }

  #pragma unroll
  for (int ks = 0; ks < 8; ++ks) {
    const int off = (ks * 2 + half) * 256;
    v8bf a0  = *(const v8bf*)(Ap + off);
    v8bf a1  = *(const v8bf*)(Ap + 4096 + off);
    v8bf b0a = *(const v8bf*)(Bpa + off);
    v8bf b1a = *(const v8bf*)(Bpa + 4096 + off);
    v8bf b0b = *(const v8bf*)(Bpb + off);
    v8bf b1b = *(const v8bf*)(Bpb + 4096 + off);
    aca[0][0] = MFMA32(a0, b0a, aca[0][0]);
    aca[0][1] = MFMA32(a0, b1a, aca[0][1]);
    aca[1][0] = MFMA32(a1, b0a, aca[1][0]);
    aca[1][1] = MFMA32(a1, b1a, aca[1][1]);
    acb[0][0] = MFMA32(a0, b0b, acb[0][0]);
    acb[0][1] = MFMA32(a0, b1b, acb[0][1]);
    acb[1][0] = MFMA32(a1, b0b, acb[1][0]);
    acb[1][1] = MFMA32(a1, b1b, acb[1][1]);
  }

  // ---- P writes for both tiles: P[p][c*32+d] = outer * rnorm ----
  #pragma unroll
  for (int ti = 0; ti < 2; ++ti) {
    #pragma unroll
    for (int tj = 0; tj < 2; ++tj) {
      const int it = mh * 2 + ti, jt = nq * 2 + tj;
      const int p = it * 8 + jt;
      const float rna = rnorm[(by * 4 + it) * NRES + bxp * 16 + jt];
      const float rnb = rnorm[(by * 4 + it) * NRES + bxp * 16 + 8 + jt];
      #pragma unroll
      for (int r = 0; r < 16; ++r) {
        int cc = (r & 3) + 8 * (r >> 2) + 4 * half;
        Ps[0][p * 1032 + cc * 32 + l31] = (__bf16)(aca[ti][tj][r] * rna);
        Ps[1][p * 1032 + cc * 32 + l31] = (__bf16)(acb[ti][tj][r] * rnb);
      }
    }
  }

  // ---- GEMM2 wot prefetch: issue BEFORE the barrier ----
  const __bf16* wp =
      wot4 + ((size_t)((zg * 64 + kh * 32) * 64) + half * 32 + l31) * 8;
  v8bf wb[8];
  #pragma unroll
  for (int u = 0; u < 8; ++u)
    wb[u] = *(const v8bf*)(wp + u * 512);
  const float bz = bo[zg * 32 + l31];

  __syncthreads();

  // ---- GEMM2 dual: one wot stream feeds both tiles (K-split kh) ----
  const __bf16* ppa = &Ps[0][l31 * 1032 + kh * 512 + half * 8];
  const __bf16* ppb = &Ps[1][l31 * 1032 + kh * 512 + half * 8];

  v16f c2a, c2b;
  #pragma unroll
  for (int r = 0; r < 16; ++r) { c2a[r] = 0.f; c2b[r] = 0.f; }

  #pragma unroll
  for (int g = 0; g < 4; ++g) {
    #pragma unroll
    for (int u = 0; u < 8; ++u) {
      const int kk = g * 8 + u;
      v8bf bb = wb[u];
      if (g < 3) wb[u] = *(const v8bf*)(wp + (kk + 8) * 512);
      v8bf aaa = *(const v8bf*)(ppa + kk * 16);
      v8bf aab = *(const v8bf*)(ppb + kk * 16);
      c2a = MFMA32(aaa, bb, c2a);
      c2b = MFMA32(aab, bb, c2b);
    }
  }

  // kh==1 partials -> bf16 region (no Ps aliasing, no extra barrier)
  if (kh == 1) {
    #pragma unroll
    for (int r = 0; r < 16; ++r) {
      int cc = (r & 3) + 8 * (r >> 2) + 4 * half;
      redb[0][zg * 1024 + cc * 32 + l31] = (__bf16)c2a[r];
      redb[1][zg * 1024 + cc * 32 + l31] = (__bf16)c2b[r];
    }
  }
  __syncthreads();

  if (kh == 0) {
    #pragma unroll
    for (int r = 0; r < 16; ++r) {
      int cc = (r & 3) + 8 * (r >> 2) + 4 * half;   // = p row
      int i = by * 4 + (cc >> 3);
      float va = c2a[r] + (float)redb[0][zg * 1024 + cc * 32 + l31] + bz;
      float vb = c2b[r] + (float)redb[1][zg * 1024 + cc * 32 + l31] + bz;
      out[((size_t)i * NRES + bxp * 16 + (cc & 7)) * CZQ + zg * 32 + l31] = va;
      out[((size_t)i * NRES + bxp * 16 + 8 + (cc & 7)) * CZQ + zg * 32 + l31] = vb;
    }
  }
}

extern "C" void kernel_launch(void* const* d_in, const int* in_sizes, int n_in,
                              void* d_out, int out_size, void* d_ws, size_t ws_size,
                              hipStream_t stream) {
  const float* msa  = (const float*)d_in[0];
  const float* mask = (const float*)d_in[1];
  const float* lnw  = (const float*)d_in[2];
  const float* lnb  = (const float*)d_in[3];
  const float* wl   = (const float*)d_in[4];
  const float* bl   = (const float*)d_in[5];
  const float* wr   = (const float*)d_in[6];
  const float* br   = (const float*)d_in[7];
  const float* wo   = (const float*)d_in[8];
  const float* bo   = (const float*)d_in[9];
  float* out = (float*)d_out;

  char* ws = (char*)d_ws;
  __bf16* At2   = (__bf16*)(ws);                    // 2 MB
  __bf16* Bt2   = (__bf16*)(ws + 2097152);          // 2 MB
  float*  rnorm = (float*)(ws + 4194304);           // 256 KB
  __bf16* wot4  = (__bf16*)(ws + 4456448);          // 256 KB

  fusedA_kernel<<<1024, 256, 0, stream>>>(msa, lnw, lnb, wl, wr, mask, wo,
                                          bl, br, At2, Bt2, rnorm, wot4);
  outer_kernel<<<dim3(16, 64), 512, 0, stream>>>(At2, Bt2, rnorm, wot4, bo, out);
}